// Round 17
// baseline (756.331 us; speedup 1.0000x reference)
//
#include <hip/hip_runtime.h>
#include <hip/hip_fp16.h>
#include <math.h>

// ---------------------------------------------------------------------------
// GINE 2-layer GNN, N=100K nodes (D 32->64->64), E=3.2M edges, ED=16.
// Round 17: R16 (745us) + two micro-opts on the remaining slack:
//   (1) scatter ILP x2: two independent atomic->store chains per 4-lane team
//       per iteration (kernel is MLP-bound: VALU 3%, occ 84%, pinned ~199us
//       across 4 formulations).
//   (2) hist int4 dst reads (4 edges/thread/iter).
// Everything else byte-identical to R16 (f16 eas + dot2 agg2 / cvt+fma agg1,
// fp32 We1/x/h1 layer-1 path, f16 h1b gather copy, de-scaffolded agg loops).
// ---------------------------------------------------------------------------

#define IMIN(a, b) ((a) < (b) ? (a) : (b))

// f16 helpers
__device__ __forceinline__ unsigned packh2(float a, float b) {
  __half2 h = __floats2half2_rn(a, b);
  return *reinterpret_cast<unsigned*>(&h);
}
__device__ __forceinline__ float fmlo(unsigned u, float w, float c) {
  __half2 h = *reinterpret_cast<__half2*>(&u);
  return fmaf(__half2float(__low2half(h)), w, c);
}
__device__ __forceinline__ float fmhi(unsigned u, float w, float c) {
  __half2 h = *reinterpret_cast<__half2*>(&u);
  return fmaf(__half2float(__high2half(h)), w, c);
}
__device__ __forceinline__ float h2f(unsigned short u) {
  return __half2float(__ushort_as_half(u));
}
// D = a.f16[0]*b.f16[0] + a.f16[1]*b.f16[1] + c ; a is wave-uniform SGPR
__device__ __forceinline__ float dot2f16_s(unsigned a, unsigned b, float c) {
  float r;
  asm("v_dot2_f32_f16 %0, %1, %2, %3" : "=v"(r) : "s"(a), "v"(b), "v"(c));
  return r;
}

// ============================ sort pipeline ================================

__global__ __launch_bounds__(256) void k_hist(
    const int* __restrict__ dst, int* __restrict__ count, int E)
{
  const int tid = blockIdx.x * blockDim.x + threadIdx.x;
  const int stride = gridDim.x * blockDim.x;
  const int E4 = E >> 2;
  const int4* d4 = (const int4*)dst;
  for (int i = tid; i < E4; i += stride) {
    const int4 v = d4[i];
    atomicAdd(&count[v.x], 1);
    atomicAdd(&count[v.y], 1);
    atomicAdd(&count[v.z], 1);
    atomicAdd(&count[v.w], 1);
  }
  for (int e = (E4 << 2) + tid; e < E; e += stride)
    atomicAdd(&count[dst[e]], 1);
}

__global__ __launch_bounds__(256) void k_scan1(
    const int* __restrict__ cnt, int* __restrict__ exc,
    int* __restrict__ bsum, int M)
{
  __shared__ int wtot[4];
  const int t = threadIdx.x, lane = t & 63, wv = t >> 6;
  const int base = blockIdx.x * 1024 + t * 4;
  const int v0 = (base + 0 < M) ? cnt[base + 0] : 0;
  const int v1 = (base + 1 < M) ? cnt[base + 1] : 0;
  const int v2 = (base + 2 < M) ? cnt[base + 2] : 0;
  const int v3 = (base + 3 < M) ? cnt[base + 3] : 0;
  const int tsum = v0 + v1 + v2 + v3;
  int x = tsum;
#pragma unroll
  for (int off = 1; off < 64; off <<= 1) {
    const int y = __shfl_up(x, off, 64);
    if (lane >= off) x += y;
  }
  if (lane == 63) wtot[wv] = x;
  __syncthreads();
  int woff = 0;
#pragma unroll
  for (int w = 0; w < 4; ++w)
    if (w < wv) woff += wtot[w];
  int run = woff + x - tsum;
  if (base + 0 < M) exc[base + 0] = run;
  run += v0;
  if (base + 1 < M) exc[base + 1] = run;
  run += v1;
  if (base + 2 < M) exc[base + 2] = run;
  run += v2;
  if (base + 3 < M) exc[base + 3] = run;
  if (t == 255) bsum[blockIdx.x] = woff + x;
}

__global__ void k_scan2(int* __restrict__ bsum, int nb)
{
  if (threadIdx.x == 0) {
    int r = 0;
    for (int i = 0; i < nb; ++i) { const int t = bsum[i]; bsum[i] = r; r += t; }
  }
}

__global__ __launch_bounds__(256) void k_scan3(
    int* __restrict__ start, int* __restrict__ cursor,
    const int* __restrict__ bsum, int M)
{
  for (int i = blockIdx.x * blockDim.x + threadIdx.x; i < M;
       i += gridDim.x * blockDim.x) {
    const int s = start[i] + bsum[i >> 10];
    start[i] = s;
    cursor[i] = s;
  }
}

// combined scatter, ILP x2: 4 threads/edge-pair; lane 0 issues two
// independent atomics; each sub converts+stores two 8B payload pieces.
__global__ __launch_bounds__(256) void k_scatter_h(
    const int* __restrict__ src, const int* __restrict__ dst,
    const float4* __restrict__ ea4, int* __restrict__ cursor,
    int* __restrict__ srcs, uint2* __restrict__ easH, int E)
{
  const long tid0 = (long)blockIdx.x * blockDim.x + threadIdx.x;
  const long stride = (long)gridDim.x * blockDim.x;
  const int sub = threadIdx.x & 3;
  const long total = (long)E * 4;
  for (long t = tid0; t < total; t += 2 * stride) {
    const long t2 = t + stride;
    const int eA = (int)(t >> 2);
    const bool hasB = t2 < total;
    const int eB = hasB ? (int)(t2 >> 2) : eA;
    int posA = 0, posB = 0;
    if (sub == 0) {
      posA = atomicAdd(&cursor[dst[eA]], 1);
      if (hasB) posB = atomicAdd(&cursor[dst[eB]], 1);
    }
    posA = __shfl(posA, 0, 4);
    posB = __shfl(posB, 0, 4);
    const float4 vA = ea4[(size_t)eA * 4 + sub];
    float4 vB;
    if (hasB) vB = ea4[(size_t)eB * 4 + sub];
    if (sub == 0) {
      srcs[posA] = src[eA];
      if (hasB) srcs[posB] = src[eB];
    }
    uint2 wA;
    wA.x = packh2(vA.x, vA.y);
    wA.y = packh2(vA.z, vA.w);
    easH[(size_t)posA * 4 + sub] = wA;
    if (hasB) {
      uint2 wB;
      wB.x = packh2(vB.x, vB.y);
      wB.y = packh2(vB.z, vB.w);
      easH[(size_t)posB * 4 + sub] = wB;
    }
  }
}

// mode-1 fallback scatter: perm tokens only
__global__ __launch_bounds__(256) void k_scatter_perm(
    const int* __restrict__ dst, int* __restrict__ cursor,
    int* __restrict__ perm, int E)
{
  for (int e = blockIdx.x * blockDim.x + threadIdx.x; e < E;
       e += gridDim.x * blockDim.x) {
    const int pos = atomicAdd(&cursor[dst[e]], 1);
    perm[pos] = e;
  }
}

// ============ fused edge-embed + aggregate (f16 eas) =======================

// agg2: SGPR-fed v_dot2_f32_f16; steady-state loop has no clamps/guards.
__global__ __launch_bounds__(256, 8) void k_agg2_h(
    const unsigned short* __restrict__ h1b, const int4* __restrict__ EH,
    const int* __restrict__ srcs, const int* __restrict__ start,
    const float* __restrict__ We, const float* __restrict__ be,
    float* __restrict__ aggr, int N)
{
  const int lane = threadIdx.x & 63;
  unsigned wcolp[8];
#pragma unroll
  for (int c = 0; c < 8; ++c)
    wcolp[c] = packh2(We[(2 * c) * 64 + lane], We[(2 * c + 1) * 64 + lane]);
  const float bias = be[lane];
  const int wid = (blockIdx.x * blockDim.x + threadIdx.x) >> 6;
  const int nw = (gridDim.x * blockDim.x) >> 6;
  for (int d = wid; d < N; d += nw) {
    const int beg = __builtin_amdgcn_readfirstlane(start[d]);
    const int end = __builtin_amdgcn_readfirstlane(start[d + 1]);
    float acc = 0.f;
    const int nfull = (end - beg) & ~3;
    const int end4 = beg + nfull;
    for (int i = beg; i < end4; i += 4) {
      int s0 = srcs[i + 0], s1 = srcs[i + 1], s2 = srcs[i + 2], s3 = srcs[i + 3];
      const int4 a0 = EH[(size_t)(i + 0) * 2 + 0], b0 = EH[(size_t)(i + 0) * 2 + 1];
      const int4 a1 = EH[(size_t)(i + 1) * 2 + 0], b1 = EH[(size_t)(i + 1) * 2 + 1];
      const int4 a2 = EH[(size_t)(i + 2) * 2 + 0], b2 = EH[(size_t)(i + 2) * 2 + 1];
      const int4 a3 = EH[(size_t)(i + 3) * 2 + 0], b3 = EH[(size_t)(i + 3) * 2 + 1];
      const float hv0 = h2f(h1b[(size_t)s0 * 64 + lane]);
      const float hv1 = h2f(h1b[(size_t)s1 * 64 + lane]);
      const float hv2 = h2f(h1b[(size_t)s2 * 64 + lane]);
      const float hv3 = h2f(h1b[(size_t)s3 * 64 + lane]);
      float m0 = bias, m1 = bias, m2 = bias, m3 = bias;
      m0 = dot2f16_s((unsigned)a0.x, wcolp[0], m0);
      m0 = dot2f16_s((unsigned)a0.y, wcolp[1], m0);
      m0 = dot2f16_s((unsigned)a0.z, wcolp[2], m0);
      m0 = dot2f16_s((unsigned)a0.w, wcolp[3], m0);
      m0 = dot2f16_s((unsigned)b0.x, wcolp[4], m0);
      m0 = dot2f16_s((unsigned)b0.y, wcolp[5], m0);
      m0 = dot2f16_s((unsigned)b0.z, wcolp[6], m0);
      m0 = dot2f16_s((unsigned)b0.w, wcolp[7], m0);
      m1 = dot2f16_s((unsigned)a1.x, wcolp[0], m1);
      m1 = dot2f16_s((unsigned)a1.y, wcolp[1], m1);
      m1 = dot2f16_s((unsigned)a1.z, wcolp[2], m1);
      m1 = dot2f16_s((unsigned)a1.w, wcolp[3], m1);
      m1 = dot2f16_s((unsigned)b1.x, wcolp[4], m1);
      m1 = dot2f16_s((unsigned)b1.y, wcolp[5], m1);
      m1 = dot2f16_s((unsigned)b1.z, wcolp[6], m1);
      m1 = dot2f16_s((unsigned)b1.w, wcolp[7], m1);
      m2 = dot2f16_s((unsigned)a2.x, wcolp[0], m2);
      m2 = dot2f16_s((unsigned)a2.y, wcolp[1], m2);
      m2 = dot2f16_s((unsigned)a2.z, wcolp[2], m2);
      m2 = dot2f16_s((unsigned)a2.w, wcolp[3], m2);
      m2 = dot2f16_s((unsigned)b2.x, wcolp[4], m2);
      m2 = dot2f16_s((unsigned)b2.y, wcolp[5], m2);
      m2 = dot2f16_s((unsigned)b2.z, wcolp[6], m2);
      m2 = dot2f16_s((unsigned)b2.w, wcolp[7], m2);
      m3 = dot2f16_s((unsigned)a3.x, wcolp[0], m3);
      m3 = dot2f16_s((unsigned)a3.y, wcolp[1], m3);
      m3 = dot2f16_s((unsigned)a3.z, wcolp[2], m3);
      m3 = dot2f16_s((unsigned)a3.w, wcolp[3], m3);
      m3 = dot2f16_s((unsigned)b3.x, wcolp[4], m3);
      m3 = dot2f16_s((unsigned)b3.y, wcolp[5], m3);
      m3 = dot2f16_s((unsigned)b3.z, wcolp[6], m3);
      m3 = dot2f16_s((unsigned)b3.w, wcolp[7], m3);
      acc += fmaxf(hv0 + m0, 0.f);
      acc += fmaxf(hv1 + m1, 0.f);
      acc += fmaxf(hv2 + m2, 0.f);
      acc += fmaxf(hv3 + m3, 0.f);
    }
    for (int i = end4; i < end; ++i) {  // tail (<=3 edges)
      const int s = srcs[i];
      const int4 a = EH[(size_t)i * 2 + 0], b = EH[(size_t)i * 2 + 1];
      const float hv = h2f(h1b[(size_t)s * 64 + lane]);
      float m = bias;
      m = dot2f16_s((unsigned)a.x, wcolp[0], m);
      m = dot2f16_s((unsigned)a.y, wcolp[1], m);
      m = dot2f16_s((unsigned)a.z, wcolp[2], m);
      m = dot2f16_s((unsigned)a.w, wcolp[3], m);
      m = dot2f16_s((unsigned)b.x, wcolp[4], m);
      m = dot2f16_s((unsigned)b.y, wcolp[5], m);
      m = dot2f16_s((unsigned)b.z, wcolp[6], m);
      m = dot2f16_s((unsigned)b.w, wcolp[7], m);
      acc += fmaxf(hv + m, 0.f);
    }
    aggr[(size_t)d * 64 + lane] = acc;
  }
}

// agg1: fp32 We1, f16 ea via cvt+fma; half-wave split, steady-state
// 8-edge blocks (4 per half-wave) with no clamps/guards.
__global__ __launch_bounds__(256, 4) void k_agg1_h(
    const float* __restrict__ x, const int4* __restrict__ EH,
    const int* __restrict__ srcs, const int* __restrict__ start,
    const float* __restrict__ We, const float* __restrict__ be,
    float* __restrict__ aggr, int N)
{
  const int lane = threadIdx.x & 63;
  const int j = lane & 31;
  const int o = (lane >> 5) * 4;  // half-wave base within 8-block
  float wcol[16];
#pragma unroll
  for (int k = 0; k < 16; ++k) wcol[k] = We[k * 32 + j];
  const float bias = be[j];
  const int wid = (blockIdx.x * blockDim.x + threadIdx.x) >> 6;
  const int nw = (gridDim.x * blockDim.x) >> 6;
  for (int d = wid; d < N; d += nw) {
    const int beg = __builtin_amdgcn_readfirstlane(start[d]);
    const int end = __builtin_amdgcn_readfirstlane(start[d + 1]);
    float acc = 0.f;
    const int nfull = (end - beg) & ~7;
    const int end8 = beg + nfull;
    for (int i = beg; i < end8; i += 8) {
      const int i0 = i + o;
      const int s0 = srcs[i0 + 0], s1 = srcs[i0 + 1];
      const int s2 = srcs[i0 + 2], s3 = srcs[i0 + 3];
      const int4 a0 = EH[(size_t)(i0 + 0) * 2 + 0], b0 = EH[(size_t)(i0 + 0) * 2 + 1];
      const int4 a1 = EH[(size_t)(i0 + 1) * 2 + 0], b1 = EH[(size_t)(i0 + 1) * 2 + 1];
      const int4 a2 = EH[(size_t)(i0 + 2) * 2 + 0], b2 = EH[(size_t)(i0 + 2) * 2 + 1];
      const int4 a3 = EH[(size_t)(i0 + 3) * 2 + 0], b3 = EH[(size_t)(i0 + 3) * 2 + 1];
      const float x0 = x[(size_t)s0 * 32 + j];
      const float x1 = x[(size_t)s1 * 32 + j];
      const float x2 = x[(size_t)s2 * 32 + j];
      const float x3 = x[(size_t)s3 * 32 + j];
      float m0 = bias, m1 = bias, m2 = bias, m3 = bias;
      m0 = fmlo((unsigned)a0.x, wcol[0],  m0); m0 = fmhi((unsigned)a0.x, wcol[1],  m0);
      m0 = fmlo((unsigned)a0.y, wcol[2],  m0); m0 = fmhi((unsigned)a0.y, wcol[3],  m0);
      m0 = fmlo((unsigned)a0.z, wcol[4],  m0); m0 = fmhi((unsigned)a0.z, wcol[5],  m0);
      m0 = fmlo((unsigned)a0.w, wcol[6],  m0); m0 = fmhi((unsigned)a0.w, wcol[7],  m0);
      m0 = fmlo((unsigned)b0.x, wcol[8],  m0); m0 = fmhi((unsigned)b0.x, wcol[9],  m0);
      m0 = fmlo((unsigned)b0.y, wcol[10], m0); m0 = fmhi((unsigned)b0.y, wcol[11], m0);
      m0 = fmlo((unsigned)b0.z, wcol[12], m0); m0 = fmhi((unsigned)b0.z, wcol[13], m0);
      m0 = fmlo((unsigned)b0.w, wcol[14], m0); m0 = fmhi((unsigned)b0.w, wcol[15], m0);
      m1 = fmlo((unsigned)a1.x, wcol[0],  m1); m1 = fmhi((unsigned)a1.x, wcol[1],  m1);
      m1 = fmlo((unsigned)a1.y, wcol[2],  m1); m1 = fmhi((unsigned)a1.y, wcol[3],  m1);
      m1 = fmlo((unsigned)a1.z, wcol[4],  m1); m1 = fmhi((unsigned)a1.z, wcol[5],  m1);
      m1 = fmlo((unsigned)a1.w, wcol[6],  m1); m1 = fmhi((unsigned)a1.w, wcol[7],  m1);
      m1 = fmlo((unsigned)b1.x, wcol[8],  m1); m1 = fmhi((unsigned)b1.x, wcol[9],  m1);
      m1 = fmlo((unsigned)b1.y, wcol[10], m1); m1 = fmhi((unsigned)b1.y, wcol[11], m1);
      m1 = fmlo((unsigned)b1.z, wcol[12], m1); m1 = fmhi((unsigned)b1.z, wcol[13], m1);
      m1 = fmlo((unsigned)b1.w, wcol[14], m1); m1 = fmhi((unsigned)b1.w, wcol[15], m1);
      m2 = fmlo((unsigned)a2.x, wcol[0],  m2); m2 = fmhi((unsigned)a2.x, wcol[1],  m2);
      m2 = fmlo((unsigned)a2.y, wcol[2],  m2); m2 = fmhi((unsigned)a2.y, wcol[3],  m2);
      m2 = fmlo((unsigned)a2.z, wcol[4],  m2); m2 = fmhi((unsigned)a2.z, wcol[5],  m2);
      m2 = fmlo((unsigned)a2.w, wcol[6],  m2); m2 = fmhi((unsigned)a2.w, wcol[7],  m2);
      m2 = fmlo((unsigned)b2.x, wcol[8],  m2); m2 = fmhi((unsigned)b2.x, wcol[9],  m2);
      m2 = fmlo((unsigned)b2.y, wcol[10], m2); m2 = fmhi((unsigned)b2.y, wcol[11], m2);
      m2 = fmlo((unsigned)b2.z, wcol[12], m2); m2 = fmhi((unsigned)b2.z, wcol[13], m2);
      m2 = fmlo((unsigned)b2.w, wcol[14], m2); m2 = fmhi((unsigned)b2.w, wcol[15], m2);
      m3 = fmlo((unsigned)a3.x, wcol[0],  m3); m3 = fmhi((unsigned)a3.x, wcol[1],  m3);
      m3 = fmlo((unsigned)a3.y, wcol[2],  m3); m3 = fmhi((unsigned)a3.y, wcol[3],  m3);
      m3 = fmlo((unsigned)a3.z, wcol[4],  m3); m3 = fmhi((unsigned)a3.z, wcol[5],  m3);
      m3 = fmlo((unsigned)a3.w, wcol[6],  m3); m3 = fmhi((unsigned)a3.w, wcol[7],  m3);
      m3 = fmlo((unsigned)b3.x, wcol[8],  m3); m3 = fmhi((unsigned)b3.x, wcol[9],  m3);
      m3 = fmlo((unsigned)b3.y, wcol[10], m3); m3 = fmhi((unsigned)b3.y, wcol[11], m3);
      m3 = fmlo((unsigned)b3.z, wcol[12], m3); m3 = fmhi((unsigned)b3.z, wcol[13], m3);
      m3 = fmlo((unsigned)b3.w, wcol[14], m3); m3 = fmhi((unsigned)b3.w, wcol[15], m3);
      acc += fmaxf(x0 + m0, 0.f);
      acc += fmaxf(x1 + m1, 0.f);
      acc += fmaxf(x2 + m2, 0.f);
      acc += fmaxf(x3 + m3, 0.f);
    }
    // tail (<=7 edges): o==0 lanes take even offsets, o==4 take odd
    for (int i = end8 + (o >> 2 ? 1 : 0); i < end; i += 2) {
      const int s = srcs[i];
      const int4 a = EH[(size_t)i * 2 + 0], b = EH[(size_t)i * 2 + 1];
      const float xv = x[(size_t)s * 32 + j];
      float m = bias;
      m = fmlo((unsigned)a.x, wcol[0],  m); m = fmhi((unsigned)a.x, wcol[1],  m);
      m = fmlo((unsigned)a.y, wcol[2],  m); m = fmhi((unsigned)a.y, wcol[3],  m);
      m = fmlo((unsigned)a.z, wcol[4],  m); m = fmhi((unsigned)a.z, wcol[5],  m);
      m = fmlo((unsigned)a.w, wcol[6],  m); m = fmhi((unsigned)a.w, wcol[7],  m);
      m = fmlo((unsigned)b.x, wcol[8],  m); m = fmhi((unsigned)b.x, wcol[9],  m);
      m = fmlo((unsigned)b.y, wcol[10], m); m = fmhi((unsigned)b.y, wcol[11], m);
      m = fmlo((unsigned)b.z, wcol[12], m); m = fmhi((unsigned)b.z, wcol[13], m);
      m = fmlo((unsigned)b.w, wcol[14], m); m = fmhi((unsigned)b.w, wcol[15], m);
      acc += fmaxf(xv + m, 0.f);
    }
    acc += __shfl(acc, lane ^ 32, 64);
    if (lane < 32) aggr[(size_t)d * 32 + j] = acc;
  }
}

// ================= mode-1 fallback (fp32 ea via perm) ======================

__global__ __launch_bounds__(256, 4) void k_agg2_f(
    const float* __restrict__ h1, const float* __restrict__ EA,
    const int* __restrict__ SRCS, const int* __restrict__ perm,
    const int* __restrict__ start, const float* __restrict__ We,
    const float* __restrict__ be, float* __restrict__ aggr, int N)
{
  const int lane = threadIdx.x & 63;
  float wcol[16];
#pragma unroll
  for (int k = 0; k < 16; ++k) wcol[k] = We[k * 64 + lane];
  const float bias = be[lane];
  const float4* EA4 = (const float4*)EA;
  const int wid = (blockIdx.x * blockDim.x + threadIdx.x) >> 6;
  const int nw = (gridDim.x * blockDim.x) >> 6;
  for (int d = wid; d < N; d += nw) {
    const int beg = __builtin_amdgcn_readfirstlane(start[d]);
    const int end = __builtin_amdgcn_readfirstlane(start[d + 1]);
    float acc = 0.f;
    for (int i = beg; i < end; ++i) {
      const int a = perm[i];
      const int s = SRCS[a];
      float4 ev[4];
#pragma unroll
      for (int c = 0; c < 4; ++c) ev[c] = EA4[(size_t)a * 4 + c];
      const float hv = h1[(size_t)s * 64 + lane];
      float m = bias;
#pragma unroll
      for (int c = 0; c < 4; ++c) {
        m = fmaf(ev[c].x, wcol[4 * c + 0], m);
        m = fmaf(ev[c].y, wcol[4 * c + 1], m);
        m = fmaf(ev[c].z, wcol[4 * c + 2], m);
        m = fmaf(ev[c].w, wcol[4 * c + 3], m);
      }
      acc += fmaxf(hv + m, 0.f);
    }
    aggr[(size_t)d * 64 + lane] = acc;
  }
}

__global__ __launch_bounds__(256, 4) void k_agg1_f(
    const float* __restrict__ x, const float* __restrict__ EA,
    const int* __restrict__ SRCS, const int* __restrict__ perm,
    const int* __restrict__ start, const float* __restrict__ We,
    const float* __restrict__ be, float* __restrict__ aggr, int N)
{
  const int lane = threadIdx.x & 63;
  const int j = lane & 31;
  const int p = lane >> 5;
  float wcol[16];
#pragma unroll
  for (int k = 0; k < 16; ++k) wcol[k] = We[k * 32 + j];
  const float bias = be[j];
  const float4* EA4 = (const float4*)EA;
  const int wid = (blockIdx.x * blockDim.x + threadIdx.x) >> 6;
  const int nw = (gridDim.x * blockDim.x) >> 6;
  for (int d = wid; d < N; d += nw) {
    const int beg = __builtin_amdgcn_readfirstlane(start[d]);
    const int end = __builtin_amdgcn_readfirstlane(start[d + 1]);
    float acc = 0.f;
    for (int i = beg + p; i < end; i += 2) {
      const int a = perm[i];
      const int s = SRCS[a];
      float4 ev[4];
#pragma unroll
      for (int c = 0; c < 4; ++c) ev[c] = EA4[(size_t)a * 4 + c];
      const float xv = x[(size_t)s * 32 + j];
      float m = bias;
#pragma unroll
      for (int c = 0; c < 4; ++c) {
        m = fmaf(ev[c].x, wcol[4 * c + 0], m);
        m = fmaf(ev[c].y, wcol[4 * c + 1], m);
        m = fmaf(ev[c].z, wcol[4 * c + 2], m);
        m = fmaf(ev[c].w, wcol[4 * c + 3], m);
      }
      acc += fmaxf(xv + m, 0.f);
    }
    acc += __shfl(acc, lane ^ 32, 64);
    if (lane < 32) aggr[(size_t)d * 32 + j] = acc;
  }
}

// ============================ node MLPs + head =============================

__global__ __launch_bounds__(256) void k_node1(
    const float* __restrict__ x, const float* __restrict__ aggr,
    const float* __restrict__ Wa, const float* __restrict__ ba,
    const float* __restrict__ Wb, const float* __restrict__ bb,
    float* __restrict__ h1, unsigned short* __restrict__ h1b, int N)
{
  __shared__ float hsh[4][32];
  __shared__ float tsh[4][64];
  const int lane = threadIdx.x & 63;
  const int wv = threadIdx.x >> 6;
  float wa[32], wb[64];
#pragma unroll
  for (int k = 0; k < 32; ++k) wa[k] = Wa[k * 64 + lane];
#pragma unroll
  for (int k = 0; k < 64; ++k) wb[k] = Wb[k * 64 + lane];
  const float ba_l = ba[lane], bb_l = bb[lane];
  const int wid = (blockIdx.x * blockDim.x + threadIdx.x) >> 6;
  const int nw = (gridDim.x * blockDim.x) >> 6;
  const float4* hp4 = (const float4*)(&hsh[wv][0]);
  const float4* tp = (const float4*)(&tsh[wv][0]);
  for (int n = wid; n < N; n += nw) {
    if (lane < 32)
      hsh[wv][lane] = x[(size_t)n * 32 + lane] + aggr[(size_t)n * 32 + lane];
    float t = ba_l;
#pragma unroll
    for (int c = 0; c < 8; ++c) {
      const float4 hv = hp4[c];
      t = fmaf(hv.x, wa[4 * c + 0], t);
      t = fmaf(hv.y, wa[4 * c + 1], t);
      t = fmaf(hv.z, wa[4 * c + 2], t);
      t = fmaf(hv.w, wa[4 * c + 3], t);
    }
    t = fmaxf(t, 0.f);
    tsh[wv][lane] = t;
    float h = bb_l;
#pragma unroll
    for (int c = 0; c < 16; ++c) {
      const float4 tv = tp[c];
      h = fmaf(tv.x, wb[4 * c + 0], h);
      h = fmaf(tv.y, wb[4 * c + 1], h);
      h = fmaf(tv.z, wb[4 * c + 2], h);
      h = fmaf(tv.w, wb[4 * c + 3], h);
    }
    h1[(size_t)n * 64 + lane] = h;
    h1b[(size_t)n * 64 + lane] = __half_as_ushort(__float2half(h));
  }
}

__global__ __launch_bounds__(256) void k_node2(
    const float* __restrict__ h1, const float* __restrict__ aggr,
    const float* __restrict__ Wa, const float* __restrict__ ba,
    const float* __restrict__ Wb, const float* __restrict__ bb,
    float* __restrict__ gsum, int N)
{
  __shared__ float hsh[4][64];
  __shared__ float tsh[4][64];
  __shared__ float red[4][64];
  const int lane = threadIdx.x & 63;
  const int wv = threadIdx.x >> 6;
  float wa[64], wb[64];
#pragma unroll
  for (int k = 0; k < 64; ++k) wa[k] = Wa[k * 64 + lane];
#pragma unroll
  for (int k = 0; k < 64; ++k) wb[k] = Wb[k * 64 + lane];
  const float ba_l = ba[lane], bb_l = bb[lane];
  float psum = 0.f;
  const int wid = (blockIdx.x * blockDim.x + threadIdx.x) >> 6;
  const int nw = (gridDim.x * blockDim.x) >> 6;
  const float4* hp4 = (const float4*)(&hsh[wv][0]);
  const float4* tp = (const float4*)(&tsh[wv][0]);
  for (int n = wid; n < N; n += nw) {
    hsh[wv][lane] = h1[(size_t)n * 64 + lane] + aggr[(size_t)n * 64 + lane];
    float t = ba_l;
#pragma unroll
    for (int c = 0; c < 16; ++c) {
      const float4 hv = hp4[c];
      t = fmaf(hv.x, wa[4 * c + 0], t);
      t = fmaf(hv.y, wa[4 * c + 1], t);
      t = fmaf(hv.z, wa[4 * c + 2], t);
      t = fmaf(hv.w, wa[4 * c + 3], t);
    }
    t = fmaxf(t, 0.f);
    tsh[wv][lane] = t;
    float h = bb_l;
#pragma unroll
    for (int c = 0; c < 16; ++c) {
      const float4 tv = tp[c];
      h = fmaf(tv.x, wb[4 * c + 0], h);
      h = fmaf(tv.y, wb[4 * c + 1], h);
      h = fmaf(tv.z, wb[4 * c + 2], h);
      h = fmaf(tv.w, wb[4 * c + 3], h);
    }
    psum += h;
  }
  red[wv][lane] = psum;
  __syncthreads();
  if (threadIdx.x < 64) {
    const float s4 = red[0][lane] + red[1][lane] + red[2][lane] + red[3][lane];
    atomicAdd(&gsum[lane], s4);
  }
}

__global__ __launch_bounds__(256) void k_head(
    const float* __restrict__ gsum,
    const float* __restrict__ Wn1, const float* __restrict__ bn1,
    const float* __restrict__ Wn2, const float* __restrict__ bn2,
    const float* __restrict__ Ws1, const float* __restrict__ bs1,
    const float* __restrict__ Ws2, const float* __restrict__ bs2,
    const float* __restrict__ Wt1, const float* __restrict__ bt1,
    const float* __restrict__ Wt2, const float* __restrict__ bt2,
    float* __restrict__ out, float invN)
{
  __shared__ float g[64], z1[256], z2[128], sa[64], tb[64];
  const int t = threadIdx.x;
  if (t < 64) g[t] = gsum[t] * invN;
  __syncthreads();
  {
    float acc = bn1[t];
    for (int k = 0; k < 64; ++k) acc = fmaf(g[k], Wn1[k * 256 + t], acc);
    z1[t] = fmaxf(acc, 0.f);
  }
  __syncthreads();
  if (t < 128) {
    float acc = bn2[t];
    for (int k = 0; k < 256; ++k) acc = fmaf(z1[k], Wn2[k * 128 + t], acc);
    z2[t] = fmaxf(acc, 0.f);
  }
  __syncthreads();
  if (t < 64) {
    float acc = bs1[t];
    for (int k = 0; k < 128; ++k) acc = fmaf(z2[k], Ws1[k * 64 + t], acc);
    sa[t] = fmaxf(acc, 0.f);
  } else if (t < 128) {
    const int j = t - 64;
    float acc = bt1[j];
    for (int k = 0; k < 128; ++k) acc = fmaf(z2[k], Wt1[k * 64 + j], acc);
    tb[j] = fmaxf(acc, 0.f);
  }
  __syncthreads();
  if (t < 64) {
    float acc = bs2[t];
    for (int k = 0; k < 64; ++k) acc = fmaf(sa[k], Ws2[k * 64 + t], acc);
    out[t] = 1.f / (1.f + __expf(-acc));
  } else if (t < 96) {
    const int j = t - 64;
    float acc = bt2[j];
    for (int k = 0; k < 64; ++k) acc = fmaf(tb[k], Wt2[k * 32 + j], acc);
    out[64 + j] = 1.f / (1.f + __expf(-acc));
  }
}

// ================================ launch ===================================

extern "C" void kernel_launch(void* const* d_in, const int* in_sizes, int n_in,
                              void* d_out, int out_size, void* d_ws, size_t ws_size,
                              hipStream_t stream)
{
  const float* x   = (const float*)d_in[0];
  const float* ea  = (const float*)d_in[1];
  const int*   ei  = (const int*)d_in[2];
  const float* We1 = (const float*)d_in[3];  const float* be1 = (const float*)d_in[4];
  const float* W1a = (const float*)d_in[5];  const float* b1a = (const float*)d_in[6];
  const float* W1b = (const float*)d_in[7];  const float* b1b = (const float*)d_in[8];
  const float* We2 = (const float*)d_in[9];  const float* be2 = (const float*)d_in[10];
  const float* W2a = (const float*)d_in[11]; const float* b2a = (const float*)d_in[12];
  const float* W2b = (const float*)d_in[13]; const float* b2b = (const float*)d_in[14];
  const float* Wn1 = (const float*)d_in[15]; const float* bn1 = (const float*)d_in[16];
  const float* Wn2 = (const float*)d_in[17]; const float* bn2 = (const float*)d_in[18];
  const float* Ws1 = (const float*)d_in[19]; const float* bs1 = (const float*)d_in[20];
  const float* Ws2 = (const float*)d_in[21]; const float* bs2 = (const float*)d_in[22];
  const float* Wt1 = (const float*)d_in[23]; const float* bt1 = (const float*)d_in[24];
  const float* Wt2 = (const float*)d_in[25]; const float* bt2 = (const float*)d_in[26];

  const int N = in_sizes[0] / 32;
  const int E = in_sizes[1] / 16;
  const int* src = ei;
  const int* dst = ei + E;

  char* ws = (char*)d_ws;
  size_t off = 0;
  auto alloc = [&](size_t bytes) -> char* {
    char* p = ws + off;
    off = (off + bytes + 255) & ~(size_t)255;
    return p;
  };
  float* h1     = (float*)alloc((size_t)N * 64 * 4);
  unsigned short* h1b = (unsigned short*)alloc((size_t)N * 64 * 2);
  float* aggr   = (float*)alloc((size_t)N * 64 * 4);
  float* gsum   = (float*)alloc(256);
  int*   count  = (int*)alloc((size_t)(N + 1) * 4);
  int*   start  = (int*)alloc((size_t)(N + 1) * 4);
  int*   cursor = (int*)alloc((size_t)(N + 1) * 4);
  int*   bsum   = (int*)alloc(4096);
  int*   perm   = (int*)alloc((size_t)E * 4);
  const size_t base_need = off;
  int*   srcs = (int*)alloc((size_t)E * 4);
  char*  easH = alloc((size_t)E * 32);  // f16-packed [E][16]
  const size_t mat_need = off;

  const int mode = (ws_size >= mat_need) ? 2 : 1;
  (void)base_need;

  hipMemsetAsync(gsum, 0, 256, stream);

  const int M = N + 1;
  const int nb = (M + 1023) / 1024;
  const int egrid = min((E + 255) / 256, 8192);
  hipMemsetAsync(count, 0, (size_t)M * 4, stream);
  k_hist<<<min((E / 4 + 255) / 256, 4096), 256, 0, stream>>>(dst, count, E);
  k_scan1<<<nb, 256, 0, stream>>>(count, start, bsum, M);
  k_scan2<<<1, 64, 0, stream>>>(bsum, nb);
  k_scan3<<<(M + 255) / 256, 256, 0, stream>>>(start, cursor, bsum, M);
  if (mode == 2) {
    k_scatter_h<<<8192, 256, 0, stream>>>(src, dst, (const float4*)ea,
                                          cursor, srcs, (uint2*)easH, E);
    k_agg1_h<<<4096, 256, 0, stream>>>(x, (const int4*)easH, srcs, start,
                                       We1, be1, aggr, N);
    k_node1<<<2048, 256, 0, stream>>>(x, aggr, W1a, b1a, W1b, b1b, h1, h1b, N);
    k_agg2_h<<<4096, 256, 0, stream>>>(h1b, (const int4*)easH, srcs, start,
                                       We2, be2, aggr, N);
  } else {
    k_scatter_perm<<<egrid, 256, 0, stream>>>(dst, cursor, perm, E);
    k_agg1_f<<<4096, 256, 0, stream>>>(x, ea, src, perm, start, We1, be1, aggr, N);
    k_node1<<<2048, 256, 0, stream>>>(x, aggr, W1a, b1a, W1b, b1b, h1, h1b, N);
    k_agg2_f<<<4096, 256, 0, stream>>>(h1, ea, src, perm, start, We2, be2, aggr, N);
  }

  k_node2<<<2048, 256, 0, stream>>>(h1, aggr, W2a, b2a, W2b, b2b, gsum, N);
  k_head<<<1, 256, 0, stream>>>(gsum, Wn1, bn1, Wn2, bn2, Ws1, bs1, Ws2, bs2,
                                Wt1, bt1, Wt2, bt2, (float*)d_out, 1.f / (float)N);
}

// Round 18
// 740.468 us; speedup vs baseline: 1.0214x; 1.0214x over previous
//
#include <hip/hip_runtime.h>
#include <hip/hip_fp16.h>
#include <math.h>

// ---------------------------------------------------------------------------
// GINE 2-layer GNN, N=100K nodes (D 32->64->64), E=3.2M edges, ED=16.
// Round 18: revert to R16 exactly (best measured: 745us, absmax 9.8e-4).
// R17's scatter ILP x2 + hist int4 were null/slightly negative (scatter is
// at the random-partial-line RMW ceiling: ~199us across 5 formulations,
// VALU 3-4%, occ 82-84%). Final configuration:
//   - counting-sort by dst (hist/scan/combined scatter, f16 eas + srcs)
//   - agg1: fp32 We1 (layer-1 error budget), f16 ea cvt+fma, half-wave,
//     de-scaffolded steady-state loop (256,4)
//   - agg2: SGPR-fed v_dot2_f32_f16, f16 h1b gathers, de-scaffolded (256,8)
//   - node MLPs: weights-in-registers + LDS broadcast; h1 fp32 + h1b f16
//   - single-block head
// ---------------------------------------------------------------------------

#define IMIN(a, b) ((a) < (b) ? (a) : (b))

// f16 helpers
__device__ __forceinline__ unsigned packh2(float a, float b) {
  __half2 h = __floats2half2_rn(a, b);
  return *reinterpret_cast<unsigned*>(&h);
}
__device__ __forceinline__ float fmlo(unsigned u, float w, float c) {
  __half2 h = *reinterpret_cast<__half2*>(&u);
  return fmaf(__half2float(__low2half(h)), w, c);
}
__device__ __forceinline__ float fmhi(unsigned u, float w, float c) {
  __half2 h = *reinterpret_cast<__half2*>(&u);
  return fmaf(__half2float(__high2half(h)), w, c);
}
__device__ __forceinline__ float h2f(unsigned short u) {
  return __half2float(__ushort_as_half(u));
}
// D = a.f16[0]*b.f16[0] + a.f16[1]*b.f16[1] + c ; a is wave-uniform SGPR
__device__ __forceinline__ float dot2f16_s(unsigned a, unsigned b, float c) {
  float r;
  asm("v_dot2_f32_f16 %0, %1, %2, %3" : "=v"(r) : "s"(a), "v"(b), "v"(c));
  return r;
}

// ============================ sort pipeline ================================

__global__ __launch_bounds__(256) void k_hist(
    const int* __restrict__ dst, int* __restrict__ count, int E)
{
  for (int e = blockIdx.x * blockDim.x + threadIdx.x; e < E;
       e += gridDim.x * blockDim.x)
    atomicAdd(&count[dst[e]], 1);
}

__global__ __launch_bounds__(256) void k_scan1(
    const int* __restrict__ cnt, int* __restrict__ exc,
    int* __restrict__ bsum, int M)
{
  __shared__ int wtot[4];
  const int t = threadIdx.x, lane = t & 63, wv = t >> 6;
  const int base = blockIdx.x * 1024 + t * 4;
  const int v0 = (base + 0 < M) ? cnt[base + 0] : 0;
  const int v1 = (base + 1 < M) ? cnt[base + 1] : 0;
  const int v2 = (base + 2 < M) ? cnt[base + 2] : 0;
  const int v3 = (base + 3 < M) ? cnt[base + 3] : 0;
  const int tsum = v0 + v1 + v2 + v3;
  int x = tsum;
#pragma unroll
  for (int off = 1; off < 64; off <<= 1) {
    const int y = __shfl_up(x, off, 64);
    if (lane >= off) x += y;
  }
  if (lane == 63) wtot[wv] = x;
  __syncthreads();
  int woff = 0;
#pragma unroll
  for (int w = 0; w < 4; ++w)
    if (w < wv) woff += wtot[w];
  int run = woff + x - tsum;
  if (base + 0 < M) exc[base + 0] = run;
  run += v0;
  if (base + 1 < M) exc[base + 1] = run;
  run += v1;
  if (base + 2 < M) exc[base + 2] = run;
  run += v2;
  if (base + 3 < M) exc[base + 3] = run;
  if (t == 255) bsum[blockIdx.x] = woff + x;
}

__global__ void k_scan2(int* __restrict__ bsum, int nb)
{
  if (threadIdx.x == 0) {
    int r = 0;
    for (int i = 0; i < nb; ++i) { const int t = bsum[i]; bsum[i] = r; r += t; }
  }
}

__global__ __launch_bounds__(256) void k_scan3(
    int* __restrict__ start, int* __restrict__ cursor,
    const int* __restrict__ bsum, int M)
{
  for (int i = blockIdx.x * blockDim.x + threadIdx.x; i < M;
       i += gridDim.x * blockDim.x) {
    const int s = start[i] + bsum[i >> 10];
    start[i] = s;
    cursor[i] = s;
  }
}

// combined scatter: 4 threads/edge; leader grabs slot via atomic, pos
// broadcast by shfl; each sub converts 4 floats -> 4 f16 and writes 8B.
__global__ __launch_bounds__(256) void k_scatter_h(
    const int* __restrict__ src, const int* __restrict__ dst,
    const float4* __restrict__ ea4, int* __restrict__ cursor,
    int* __restrict__ srcs, uint2* __restrict__ easH, int E)
{
  const long tid0 = (long)blockIdx.x * blockDim.x + threadIdx.x;
  const long stride = (long)gridDim.x * blockDim.x;
  const int sub = threadIdx.x & 3;
  const long total = (long)E * 4;
  for (long t = tid0; t < total; t += stride) {
    const int e = (int)(t >> 2);
    int pos = 0;
    if (sub == 0) pos = atomicAdd(&cursor[dst[e]], 1);
    pos = __shfl(pos, 0, 4);
    if (sub == 0) srcs[pos] = src[e];
    const float4 v = ea4[(size_t)e * 4 + sub];
    uint2 w;
    w.x = packh2(v.x, v.y);
    w.y = packh2(v.z, v.w);
    easH[(size_t)pos * 4 + sub] = w;
  }
}

// mode-1 fallback scatter: perm tokens only
__global__ __launch_bounds__(256) void k_scatter_perm(
    const int* __restrict__ dst, int* __restrict__ cursor,
    int* __restrict__ perm, int E)
{
  for (int e = blockIdx.x * blockDim.x + threadIdx.x; e < E;
       e += gridDim.x * blockDim.x) {
    const int pos = atomicAdd(&cursor[dst[e]], 1);
    perm[pos] = e;
  }
}

// ============ fused edge-embed + aggregate (f16 eas) =======================

// agg2: SGPR-fed v_dot2_f32_f16; steady-state loop has no clamps/guards.
__global__ __launch_bounds__(256, 8) void k_agg2_h(
    const unsigned short* __restrict__ h1b, const int4* __restrict__ EH,
    const int* __restrict__ srcs, const int* __restrict__ start,
    const float* __restrict__ We, const float* __restrict__ be,
    float* __restrict__ aggr, int N)
{
  const int lane = threadIdx.x & 63;
  unsigned wcolp[8];
#pragma unroll
  for (int c = 0; c < 8; ++c)
    wcolp[c] = packh2(We[(2 * c) * 64 + lane], We[(2 * c + 1) * 64 + lane]);
  const float bias = be[lane];
  const int wid = (blockIdx.x * blockDim.x + threadIdx.x) >> 6;
  const int nw = (gridDim.x * blockDim.x) >> 6;
  for (int d = wid; d < N; d += nw) {
    const int beg = __builtin_amdgcn_readfirstlane(start[d]);
    const int end = __builtin_amdgcn_readfirstlane(start[d + 1]);
    float acc = 0.f;
    const int nfull = (end - beg) & ~3;
    const int end4 = beg + nfull;
    for (int i = beg; i < end4; i += 4) {
      int s0 = srcs[i + 0], s1 = srcs[i + 1], s2 = srcs[i + 2], s3 = srcs[i + 3];
      const int4 a0 = EH[(size_t)(i + 0) * 2 + 0], b0 = EH[(size_t)(i + 0) * 2 + 1];
      const int4 a1 = EH[(size_t)(i + 1) * 2 + 0], b1 = EH[(size_t)(i + 1) * 2 + 1];
      const int4 a2 = EH[(size_t)(i + 2) * 2 + 0], b2 = EH[(size_t)(i + 2) * 2 + 1];
      const int4 a3 = EH[(size_t)(i + 3) * 2 + 0], b3 = EH[(size_t)(i + 3) * 2 + 1];
      const float hv0 = h2f(h1b[(size_t)s0 * 64 + lane]);
      const float hv1 = h2f(h1b[(size_t)s1 * 64 + lane]);
      const float hv2 = h2f(h1b[(size_t)s2 * 64 + lane]);
      const float hv3 = h2f(h1b[(size_t)s3 * 64 + lane]);
      float m0 = bias, m1 = bias, m2 = bias, m3 = bias;
      m0 = dot2f16_s((unsigned)a0.x, wcolp[0], m0);
      m0 = dot2f16_s((unsigned)a0.y, wcolp[1], m0);
      m0 = dot2f16_s((unsigned)a0.z, wcolp[2], m0);
      m0 = dot2f16_s((unsigned)a0.w, wcolp[3], m0);
      m0 = dot2f16_s((unsigned)b0.x, wcolp[4], m0);
      m0 = dot2f16_s((unsigned)b0.y, wcolp[5], m0);
      m0 = dot2f16_s((unsigned)b0.z, wcolp[6], m0);
      m0 = dot2f16_s((unsigned)b0.w, wcolp[7], m0);
      m1 = dot2f16_s((unsigned)a1.x, wcolp[0], m1);
      m1 = dot2f16_s((unsigned)a1.y, wcolp[1], m1);
      m1 = dot2f16_s((unsigned)a1.z, wcolp[2], m1);
      m1 = dot2f16_s((unsigned)a1.w, wcolp[3], m1);
      m1 = dot2f16_s((unsigned)b1.x, wcolp[4], m1);
      m1 = dot2f16_s((unsigned)b1.y, wcolp[5], m1);
      m1 = dot2f16_s((unsigned)b1.z, wcolp[6], m1);
      m1 = dot2f16_s((unsigned)b1.w, wcolp[7], m1);
      m2 = dot2f16_s((unsigned)a2.x, wcolp[0], m2);
      m2 = dot2f16_s((unsigned)a2.y, wcolp[1], m2);
      m2 = dot2f16_s((unsigned)a2.z, wcolp[2], m2);
      m2 = dot2f16_s((unsigned)a2.w, wcolp[3], m2);
      m2 = dot2f16_s((unsigned)b2.x, wcolp[4], m2);
      m2 = dot2f16_s((unsigned)b2.y, wcolp[5], m2);
      m2 = dot2f16_s((unsigned)b2.z, wcolp[6], m2);
      m2 = dot2f16_s((unsigned)b2.w, wcolp[7], m2);
      m3 = dot2f16_s((unsigned)a3.x, wcolp[0], m3);
      m3 = dot2f16_s((unsigned)a3.y, wcolp[1], m3);
      m3 = dot2f16_s((unsigned)a3.z, wcolp[2], m3);
      m3 = dot2f16_s((unsigned)a3.w, wcolp[3], m3);
      m3 = dot2f16_s((unsigned)b3.x, wcolp[4], m3);
      m3 = dot2f16_s((unsigned)b3.y, wcolp[5], m3);
      m3 = dot2f16_s((unsigned)b3.z, wcolp[6], m3);
      m3 = dot2f16_s((unsigned)b3.w, wcolp[7], m3);
      acc += fmaxf(hv0 + m0, 0.f);
      acc += fmaxf(hv1 + m1, 0.f);
      acc += fmaxf(hv2 + m2, 0.f);
      acc += fmaxf(hv3 + m3, 0.f);
    }
    for (int i = end4; i < end; ++i) {  // tail (<=3 edges)
      const int s = srcs[i];
      const int4 a = EH[(size_t)i * 2 + 0], b = EH[(size_t)i * 2 + 1];
      const float hv = h2f(h1b[(size_t)s * 64 + lane]);
      float m = bias;
      m = dot2f16_s((unsigned)a.x, wcolp[0], m);
      m = dot2f16_s((unsigned)a.y, wcolp[1], m);
      m = dot2f16_s((unsigned)a.z, wcolp[2], m);
      m = dot2f16_s((unsigned)a.w, wcolp[3], m);
      m = dot2f16_s((unsigned)b.x, wcolp[4], m);
      m = dot2f16_s((unsigned)b.y, wcolp[5], m);
      m = dot2f16_s((unsigned)b.z, wcolp[6], m);
      m = dot2f16_s((unsigned)b.w, wcolp[7], m);
      acc += fmaxf(hv + m, 0.f);
    }
    aggr[(size_t)d * 64 + lane] = acc;
  }
}

// agg1: fp32 We1, f16 ea via cvt+fma; half-wave split, steady-state
// 8-edge blocks (4 per half-wave) with no clamps/guards.
__global__ __launch_bounds__(256, 4) void k_agg1_h(
    const float* __restrict__ x, const int4* __restrict__ EH,
    const int* __restrict__ srcs, const int* __restrict__ start,
    const float* __restrict__ We, const float* __restrict__ be,
    float* __restrict__ aggr, int N)
{
  const int lane = threadIdx.x & 63;
  const int j = lane & 31;
  const int o = (lane >> 5) * 4;  // half-wave base within 8-block
  float wcol[16];
#pragma unroll
  for (int k = 0; k < 16; ++k) wcol[k] = We[k * 32 + j];
  const float bias = be[j];
  const int wid = (blockIdx.x * blockDim.x + threadIdx.x) >> 6;
  const int nw = (gridDim.x * blockDim.x) >> 6;
  for (int d = wid; d < N; d += nw) {
    const int beg = __builtin_amdgcn_readfirstlane(start[d]);
    const int end = __builtin_amdgcn_readfirstlane(start[d + 1]);
    float acc = 0.f;
    const int nfull = (end - beg) & ~7;
    const int end8 = beg + nfull;
    for (int i = beg; i < end8; i += 8) {
      const int i0 = i + o;
      const int s0 = srcs[i0 + 0], s1 = srcs[i0 + 1];
      const int s2 = srcs[i0 + 2], s3 = srcs[i0 + 3];
      const int4 a0 = EH[(size_t)(i0 + 0) * 2 + 0], b0 = EH[(size_t)(i0 + 0) * 2 + 1];
      const int4 a1 = EH[(size_t)(i0 + 1) * 2 + 0], b1 = EH[(size_t)(i0 + 1) * 2 + 1];
      const int4 a2 = EH[(size_t)(i0 + 2) * 2 + 0], b2 = EH[(size_t)(i0 + 2) * 2 + 1];
      const int4 a3 = EH[(size_t)(i0 + 3) * 2 + 0], b3 = EH[(size_t)(i0 + 3) * 2 + 1];
      const float x0 = x[(size_t)s0 * 32 + j];
      const float x1 = x[(size_t)s1 * 32 + j];
      const float x2 = x[(size_t)s2 * 32 + j];
      const float x3 = x[(size_t)s3 * 32 + j];
      float m0 = bias, m1 = bias, m2 = bias, m3 = bias;
      m0 = fmlo((unsigned)a0.x, wcol[0],  m0); m0 = fmhi((unsigned)a0.x, wcol[1],  m0);
      m0 = fmlo((unsigned)a0.y, wcol[2],  m0); m0 = fmhi((unsigned)a0.y, wcol[3],  m0);
      m0 = fmlo((unsigned)a0.z, wcol[4],  m0); m0 = fmhi((unsigned)a0.z, wcol[5],  m0);
      m0 = fmlo((unsigned)a0.w, wcol[6],  m0); m0 = fmhi((unsigned)a0.w, wcol[7],  m0);
      m0 = fmlo((unsigned)b0.x, wcol[8],  m0); m0 = fmhi((unsigned)b0.x, wcol[9],  m0);
      m0 = fmlo((unsigned)b0.y, wcol[10], m0); m0 = fmhi((unsigned)b0.y, wcol[11], m0);
      m0 = fmlo((unsigned)b0.z, wcol[12], m0); m0 = fmhi((unsigned)b0.z, wcol[13], m0);
      m0 = fmlo((unsigned)b0.w, wcol[14], m0); m0 = fmhi((unsigned)b0.w, wcol[15], m0);
      m1 = fmlo((unsigned)a1.x, wcol[0],  m1); m1 = fmhi((unsigned)a1.x, wcol[1],  m1);
      m1 = fmlo((unsigned)a1.y, wcol[2],  m1); m1 = fmhi((unsigned)a1.y, wcol[3],  m1);
      m1 = fmlo((unsigned)a1.z, wcol[4],  m1); m1 = fmhi((unsigned)a1.z, wcol[5],  m1);
      m1 = fmlo((unsigned)a1.w, wcol[6],  m1); m1 = fmhi((unsigned)a1.w, wcol[7],  m1);
      m1 = fmlo((unsigned)b1.x, wcol[8],  m1); m1 = fmhi((unsigned)b1.x, wcol[9],  m1);
      m1 = fmlo((unsigned)b1.y, wcol[10], m1); m1 = fmhi((unsigned)b1.y, wcol[11], m1);
      m1 = fmlo((unsigned)b1.z, wcol[12], m1); m1 = fmhi((unsigned)b1.z, wcol[13], m1);
      m1 = fmlo((unsigned)b1.w, wcol[14], m1); m1 = fmhi((unsigned)b1.w, wcol[15], m1);
      m2 = fmlo((unsigned)a2.x, wcol[0],  m2); m2 = fmhi((unsigned)a2.x, wcol[1],  m2);
      m2 = fmlo((unsigned)a2.y, wcol[2],  m2); m2 = fmhi((unsigned)a2.y, wcol[3],  m2);
      m2 = fmlo((unsigned)a2.z, wcol[4],  m2); m2 = fmhi((unsigned)a2.z, wcol[5],  m2);
      m2 = fmlo((unsigned)a2.w, wcol[6],  m2); m2 = fmhi((unsigned)a2.w, wcol[7],  m2);
      m2 = fmlo((unsigned)b2.x, wcol[8],  m2); m2 = fmhi((unsigned)b2.x, wcol[9],  m2);
      m2 = fmlo((unsigned)b2.y, wcol[10], m2); m2 = fmhi((unsigned)b2.y, wcol[11], m2);
      m2 = fmlo((unsigned)b2.z, wcol[12], m2); m2 = fmhi((unsigned)b2.z, wcol[13], m2);
      m2 = fmlo((unsigned)b2.w, wcol[14], m2); m2 = fmhi((unsigned)b2.w, wcol[15], m2);
      m3 = fmlo((unsigned)a3.x, wcol[0],  m3); m3 = fmhi((unsigned)a3.x, wcol[1],  m3);
      m3 = fmlo((unsigned)a3.y, wcol[2],  m3); m3 = fmhi((unsigned)a3.y, wcol[3],  m3);
      m3 = fmlo((unsigned)a3.z, wcol[4],  m3); m3 = fmhi((unsigned)a3.z, wcol[5],  m3);
      m3 = fmlo((unsigned)a3.w, wcol[6],  m3); m3 = fmhi((unsigned)a3.w, wcol[7],  m3);
      m3 = fmlo((unsigned)b3.x, wcol[8],  m3); m3 = fmhi((unsigned)b3.x, wcol[9],  m3);
      m3 = fmlo((unsigned)b3.y, wcol[10], m3); m3 = fmhi((unsigned)b3.y, wcol[11], m3);
      m3 = fmlo((unsigned)b3.z, wcol[12], m3); m3 = fmhi((unsigned)b3.z, wcol[13], m3);
      m3 = fmlo((unsigned)b3.w, wcol[14], m3); m3 = fmhi((unsigned)b3.w, wcol[15], m3);
      acc += fmaxf(x0 + m0, 0.f);
      acc += fmaxf(x1 + m1, 0.f);
      acc += fmaxf(x2 + m2, 0.f);
      acc += fmaxf(x3 + m3, 0.f);
    }
    // tail (<=7 edges): o==0 lanes take even offsets, o==4 take odd
    for (int i = end8 + (o >> 2 ? 1 : 0); i < end; i += 2) {
      const int s = srcs[i];
      const int4 a = EH[(size_t)i * 2 + 0], b = EH[(size_t)i * 2 + 1];
      const float xv = x[(size_t)s * 32 + j];
      float m = bias;
      m = fmlo((unsigned)a.x, wcol[0],  m); m = fmhi((unsigned)a.x, wcol[1],  m);
      m = fmlo((unsigned)a.y, wcol[2],  m); m = fmhi((unsigned)a.y, wcol[3],  m);
      m = fmlo((unsigned)a.z, wcol[4],  m); m = fmhi((unsigned)a.z, wcol[5],  m);
      m = fmlo((unsigned)a.w, wcol[6],  m); m = fmhi((unsigned)a.w, wcol[7],  m);
      m = fmlo((unsigned)b.x, wcol[8],  m); m = fmhi((unsigned)b.x, wcol[9],  m);
      m = fmlo((unsigned)b.y, wcol[10], m); m = fmhi((unsigned)b.y, wcol[11], m);
      m = fmlo((unsigned)b.z, wcol[12], m); m = fmhi((unsigned)b.z, wcol[13], m);
      m = fmlo((unsigned)b.w, wcol[14], m); m = fmhi((unsigned)b.w, wcol[15], m);
      acc += fmaxf(xv + m, 0.f);
    }
    acc += __shfl(acc, lane ^ 32, 64);
    if (lane < 32) aggr[(size_t)d * 32 + j] = acc;
  }
}

// ================= mode-1 fallback (fp32 ea via perm) ======================

__global__ __launch_bounds__(256, 4) void k_agg2_f(
    const float* __restrict__ h1, const float* __restrict__ EA,
    const int* __restrict__ SRCS, const int* __restrict__ perm,
    const int* __restrict__ start, const float* __restrict__ We,
    const float* __restrict__ be, float* __restrict__ aggr, int N)
{
  const int lane = threadIdx.x & 63;
  float wcol[16];
#pragma unroll
  for (int k = 0; k < 16; ++k) wcol[k] = We[k * 64 + lane];
  const float bias = be[lane];
  const float4* EA4 = (const float4*)EA;
  const int wid = (blockIdx.x * blockDim.x + threadIdx.x) >> 6;
  const int nw = (gridDim.x * blockDim.x) >> 6;
  for (int d = wid; d < N; d += nw) {
    const int beg = __builtin_amdgcn_readfirstlane(start[d]);
    const int end = __builtin_amdgcn_readfirstlane(start[d + 1]);
    float acc = 0.f;
    for (int i = beg; i < end; ++i) {
      const int a = perm[i];
      const int s = SRCS[a];
      float4 ev[4];
#pragma unroll
      for (int c = 0; c < 4; ++c) ev[c] = EA4[(size_t)a * 4 + c];
      const float hv = h1[(size_t)s * 64 + lane];
      float m = bias;
#pragma unroll
      for (int c = 0; c < 4; ++c) {
        m = fmaf(ev[c].x, wcol[4 * c + 0], m);
        m = fmaf(ev[c].y, wcol[4 * c + 1], m);
        m = fmaf(ev[c].z, wcol[4 * c + 2], m);
        m = fmaf(ev[c].w, wcol[4 * c + 3], m);
      }
      acc += fmaxf(hv + m, 0.f);
    }
    aggr[(size_t)d * 64 + lane] = acc;
  }
}

__global__ __launch_bounds__(256, 4) void k_agg1_f(
    const float* __restrict__ x, const float* __restrict__ EA,
    const int* __restrict__ SRCS, const int* __restrict__ perm,
    const int* __restrict__ start, const float* __restrict__ We,
    const float* __restrict__ be, float* __restrict__ aggr, int N)
{
  const int lane = threadIdx.x & 63;
  const int j = lane & 31;
  const int p = lane >> 5;
  float wcol[16];
#pragma unroll
  for (int k = 0; k < 16; ++k) wcol[k] = We[k * 32 + j];
  const float bias = be[j];
  const float4* EA4 = (const float4*)EA;
  const int wid = (blockIdx.x * blockDim.x + threadIdx.x) >> 6;
  const int nw = (gridDim.x * blockDim.x) >> 6;
  for (int d = wid; d < N; d += nw) {
    const int beg = __builtin_amdgcn_readfirstlane(start[d]);
    const int end = __builtin_amdgcn_readfirstlane(start[d + 1]);
    float acc = 0.f;
    for (int i = beg + p; i < end; i += 2) {
      const int a = perm[i];
      const int s = SRCS[a];
      float4 ev[4];
#pragma unroll
      for (int c = 0; c < 4; ++c) ev[c] = EA4[(size_t)a * 4 + c];
      const float xv = x[(size_t)s * 32 + j];
      float m = bias;
#pragma unroll
      for (int c = 0; c < 4; ++c) {
        m = fmaf(ev[c].x, wcol[4 * c + 0], m);
        m = fmaf(ev[c].y, wcol[4 * c + 1], m);
        m = fmaf(ev[c].z, wcol[4 * c + 2], m);
        m = fmaf(ev[c].w, wcol[4 * c + 3], m);
      }
      acc += fmaxf(xv + m, 0.f);
    }
    acc += __shfl(acc, lane ^ 32, 64);
    if (lane < 32) aggr[(size_t)d * 32 + j] = acc;
  }
}

// ============================ node MLPs + head =============================

__global__ __launch_bounds__(256) void k_node1(
    const float* __restrict__ x, const float* __restrict__ aggr,
    const float* __restrict__ Wa, const float* __restrict__ ba,
    const float* __restrict__ Wb, const float* __restrict__ bb,
    float* __restrict__ h1, unsigned short* __restrict__ h1b, int N)
{
  __shared__ float hsh[4][32];
  __shared__ float tsh[4][64];
  const int lane = threadIdx.x & 63;
  const int wv = threadIdx.x >> 6;
  float wa[32], wb[64];
#pragma unroll
  for (int k = 0; k < 32; ++k) wa[k] = Wa[k * 64 + lane];
#pragma unroll
  for (int k = 0; k < 64; ++k) wb[k] = Wb[k * 64 + lane];
  const float ba_l = ba[lane], bb_l = bb[lane];
  const int wid = (blockIdx.x * blockDim.x + threadIdx.x) >> 6;
  const int nw = (gridDim.x * blockDim.x) >> 6;
  const float4* hp4 = (const float4*)(&hsh[wv][0]);
  const float4* tp = (const float4*)(&tsh[wv][0]);
  for (int n = wid; n < N; n += nw) {
    if (lane < 32)
      hsh[wv][lane] = x[(size_t)n * 32 + lane] + aggr[(size_t)n * 32 + lane];
    float t = ba_l;
#pragma unroll
    for (int c = 0; c < 8; ++c) {
      const float4 hv = hp4[c];
      t = fmaf(hv.x, wa[4 * c + 0], t);
      t = fmaf(hv.y, wa[4 * c + 1], t);
      t = fmaf(hv.z, wa[4 * c + 2], t);
      t = fmaf(hv.w, wa[4 * c + 3], t);
    }
    t = fmaxf(t, 0.f);
    tsh[wv][lane] = t;
    float h = bb_l;
#pragma unroll
    for (int c = 0; c < 16; ++c) {
      const float4 tv = tp[c];
      h = fmaf(tv.x, wb[4 * c + 0], h);
      h = fmaf(tv.y, wb[4 * c + 1], h);
      h = fmaf(tv.z, wb[4 * c + 2], h);
      h = fmaf(tv.w, wb[4 * c + 3], h);
    }
    h1[(size_t)n * 64 + lane] = h;
    h1b[(size_t)n * 64 + lane] = __half_as_ushort(__float2half(h));
  }
}

__global__ __launch_bounds__(256) void k_node2(
    const float* __restrict__ h1, const float* __restrict__ aggr,
    const float* __restrict__ Wa, const float* __restrict__ ba,
    const float* __restrict__ Wb, const float* __restrict__ bb,
    float* __restrict__ gsum, int N)
{
  __shared__ float hsh[4][64];
  __shared__ float tsh[4][64];
  __shared__ float red[4][64];
  const int lane = threadIdx.x & 63;
  const int wv = threadIdx.x >> 6;
  float wa[64], wb[64];
#pragma unroll
  for (int k = 0; k < 64; ++k) wa[k] = Wa[k * 64 + lane];
#pragma unroll
  for (int k = 0; k < 64; ++k) wb[k] = Wb[k * 64 + lane];
  const float ba_l = ba[lane], bb_l = bb[lane];
  float psum = 0.f;
  const int wid = (blockIdx.x * blockDim.x + threadIdx.x) >> 6;
  const int nw = (gridDim.x * blockDim.x) >> 6;
  const float4* hp4 = (const float4*)(&hsh[wv][0]);
  const float4* tp = (const float4*)(&tsh[wv][0]);
  for (int n = wid; n < N; n += nw) {
    hsh[wv][lane] = h1[(size_t)n * 64 + lane] + aggr[(size_t)n * 64 + lane];
    float t = ba_l;
#pragma unroll
    for (int c = 0; c < 16; ++c) {
      const float4 hv = hp4[c];
      t = fmaf(hv.x, wa[4 * c + 0], t);
      t = fmaf(hv.y, wa[4 * c + 1], t);
      t = fmaf(hv.z, wa[4 * c + 2], t);
      t = fmaf(hv.w, wa[4 * c + 3], t);
    }
    t = fmaxf(t, 0.f);
    tsh[wv][lane] = t;
    float h = bb_l;
#pragma unroll
    for (int c = 0; c < 16; ++c) {
      const float4 tv = tp[c];
      h = fmaf(tv.x, wb[4 * c + 0], h);
      h = fmaf(tv.y, wb[4 * c + 1], h);
      h = fmaf(tv.z, wb[4 * c + 2], h);
      h = fmaf(tv.w, wb[4 * c + 3], h);
    }
    psum += h;
  }
  red[wv][lane] = psum;
  __syncthreads();
  if (threadIdx.x < 64) {
    const float s4 = red[0][lane] + red[1][lane] + red[2][lane] + red[3][lane];
    atomicAdd(&gsum[lane], s4);
  }
}

__global__ __launch_bounds__(256) void k_head(
    const float* __restrict__ gsum,
    const float* __restrict__ Wn1, const float* __restrict__ bn1,
    const float* __restrict__ Wn2, const float* __restrict__ bn2,
    const float* __restrict__ Ws1, const float* __restrict__ bs1,
    const float* __restrict__ Ws2, const float* __restrict__ bs2,
    const float* __restrict__ Wt1, const float* __restrict__ bt1,
    const float* __restrict__ Wt2, const float* __restrict__ bt2,
    float* __restrict__ out, float invN)
{
  __shared__ float g[64], z1[256], z2[128], sa[64], tb[64];
  const int t = threadIdx.x;
  if (t < 64) g[t] = gsum[t] * invN;
  __syncthreads();
  {
    float acc = bn1[t];
    for (int k = 0; k < 64; ++k) acc = fmaf(g[k], Wn1[k * 256 + t], acc);
    z1[t] = fmaxf(acc, 0.f);
  }
  __syncthreads();
  if (t < 128) {
    float acc = bn2[t];
    for (int k = 0; k < 256; ++k) acc = fmaf(z1[k], Wn2[k * 128 + t], acc);
    z2[t] = fmaxf(acc, 0.f);
  }
  __syncthreads();
  if (t < 64) {
    float acc = bs1[t];
    for (int k = 0; k < 128; ++k) acc = fmaf(z2[k], Ws1[k * 64 + t], acc);
    sa[t] = fmaxf(acc, 0.f);
  } else if (t < 128) {
    const int j = t - 64;
    float acc = bt1[j];
    for (int k = 0; k < 128; ++k) acc = fmaf(z2[k], Wt1[k * 64 + j], acc);
    tb[j] = fmaxf(acc, 0.f);
  }
  __syncthreads();
  if (t < 64) {
    float acc = bs2[t];
    for (int k = 0; k < 64; ++k) acc = fmaf(sa[k], Ws2[k * 64 + t], acc);
    out[t] = 1.f / (1.f + __expf(-acc));
  } else if (t < 96) {
    const int j = t - 64;
    float acc = bt2[j];
    for (int k = 0; k < 64; ++k) acc = fmaf(tb[k], Wt2[k * 32 + j], acc);
    out[64 + j] = 1.f / (1.f + __expf(-acc));
  }
}

// ================================ launch ===================================

extern "C" void kernel_launch(void* const* d_in, const int* in_sizes, int n_in,
                              void* d_out, int out_size, void* d_ws, size_t ws_size,
                              hipStream_t stream)
{
  const float* x   = (const float*)d_in[0];
  const float* ea  = (const float*)d_in[1];
  const int*   ei  = (const int*)d_in[2];
  const float* We1 = (const float*)d_in[3];  const float* be1 = (const float*)d_in[4];
  const float* W1a = (const float*)d_in[5];  const float* b1a = (const float*)d_in[6];
  const float* W1b = (const float*)d_in[7];  const float* b1b = (const float*)d_in[8];
  const float* We2 = (const float*)d_in[9];  const float* be2 = (const float*)d_in[10];
  const float* W2a = (const float*)d_in[11]; const float* b2a = (const float*)d_in[12];
  const float* W2b = (const float*)d_in[13]; const float* b2b = (const float*)d_in[14];
  const float* Wn1 = (const float*)d_in[15]; const float* bn1 = (const float*)d_in[16];
  const float* Wn2 = (const float*)d_in[17]; const float* bn2 = (const float*)d_in[18];
  const float* Ws1 = (const float*)d_in[19]; const float* bs1 = (const float*)d_in[20];
  const float* Ws2 = (const float*)d_in[21]; const float* bs2 = (const float*)d_in[22];
  const float* Wt1 = (const float*)d_in[23]; const float* bt1 = (const float*)d_in[24];
  const float* Wt2 = (const float*)d_in[25]; const float* bt2 = (const float*)d_in[26];

  const int N = in_sizes[0] / 32;
  const int E = in_sizes[1] / 16;
  const int* src = ei;
  const int* dst = ei + E;

  char* ws = (char*)d_ws;
  size_t off = 0;
  auto alloc = [&](size_t bytes) -> char* {
    char* p = ws + off;
    off = (off + bytes + 255) & ~(size_t)255;
    return p;
  };
  float* h1     = (float*)alloc((size_t)N * 64 * 4);
  unsigned short* h1b = (unsigned short*)alloc((size_t)N * 64 * 2);
  float* aggr   = (float*)alloc((size_t)N * 64 * 4);
  float* gsum   = (float*)alloc(256);
  int*   count  = (int*)alloc((size_t)(N + 1) * 4);
  int*   start  = (int*)alloc((size_t)(N + 1) * 4);
  int*   cursor = (int*)alloc((size_t)(N + 1) * 4);
  int*   bsum   = (int*)alloc(4096);
  int*   perm   = (int*)alloc((size_t)E * 4);
  const size_t base_need = off;
  int*   srcs = (int*)alloc((size_t)E * 4);
  char*  easH = alloc((size_t)E * 32);  // f16-packed [E][16]
  const size_t mat_need = off;

  const int mode = (ws_size >= mat_need) ? 2 : 1;
  (void)base_need;

  hipMemsetAsync(gsum, 0, 256, stream);

  const int M = N + 1;
  const int nb = (M + 1023) / 1024;
  const int egrid = min((E + 255) / 256, 8192);
  hipMemsetAsync(count, 0, (size_t)M * 4, stream);
  k_hist<<<egrid, 256, 0, stream>>>(dst, count, E);
  k_scan1<<<nb, 256, 0, stream>>>(count, start, bsum, M);
  k_scan2<<<1, 64, 0, stream>>>(bsum, nb);
  k_scan3<<<(M + 255) / 256, 256, 0, stream>>>(start, cursor, bsum, M);
  if (mode == 2) {
    k_scatter_h<<<8192, 256, 0, stream>>>(src, dst, (const float4*)ea,
                                          cursor, srcs, (uint2*)easH, E);
    k_agg1_h<<<4096, 256, 0, stream>>>(x, (const int4*)easH, srcs, start,
                                       We1, be1, aggr, N);
    k_node1<<<2048, 256, 0, stream>>>(x, aggr, W1a, b1a, W1b, b1b, h1, h1b, N);
    k_agg2_h<<<4096, 256, 0, stream>>>(h1b, (const int4*)easH, srcs, start,
                                       We2, be2, aggr, N);
  } else {
    k_scatter_perm<<<egrid, 256, 0, stream>>>(dst, cursor, perm, E);
    k_agg1_f<<<4096, 256, 0, stream>>>(x, ea, src, perm, start, We1, be1, aggr, N);
    k_node1<<<2048, 256, 0, stream>>>(x, aggr, W1a, b1a, W1b, b1b, h1, h1b, N);
    k_agg2_f<<<4096, 256, 0, stream>>>(h1, ea, src, perm, start, We2, be2, aggr, N);
  }

  k_node2<<<2048, 256, 0, stream>>>(h1, aggr, W2a, b2a, W2b, b2b, gsum, N);
  k_head<<<1, 256, 0, stream>>>(gsum, Wn1, bn1, Wn2, bn2, Ws1, bs1, Ws2, bs2,
                                Wt1, bt1, Wt2, bt2, (float*)d_out, 1.f / (float)N);
}